// Round 4
// baseline (5696.033 us; speedup 1.0000x reference)
//
#include <hip/hip_runtime.h>
#include <hip/hip_bf16.h>

typedef __hip_bfloat16 bf16;
typedef short bf16x8 __attribute__((ext_vector_type(8)));
typedef float f32x4 __attribute__((ext_vector_type(4)));
typedef unsigned long long u64;

#define MFMA16(A, B, C) __builtin_amdgcn_mfma_f32_16x16x32_bf16(A, B, C, 0, 0, 0)

__device__ __forceinline__ float sigf(float x) { return 1.f / (1.f + __expf(-x)); }
__device__ __forceinline__ float tanh_fast(float x) { return 2.f / (1.f + __expf(-2.f * x)) - 1.f; }

// agent-scope (cross-XCD coherent, L2-bypassing) 16B h-load; relaxed so
// independent loads pipeline when hoisted ahead of their uses.
__device__ __forceinline__ bf16x8 ld_h16(const bf16* p) {
  u64 lo = __hip_atomic_load((const u64*)p, __ATOMIC_RELAXED, __HIP_MEMORY_SCOPE_AGENT);
  u64 hi = __hip_atomic_load((const u64*)p + 1, __ATOMIC_RELAXED, __HIP_MEMORY_SCOPE_AGENT);
  union { u64 q[2]; bf16x8 v; } u;
  u.q[0] = lo; u.q[1] = hi;
  return u.v;
}
__device__ __forceinline__ void st_h16(bf16* p, const bf16* lds_src) {
  u64 lo = *(const u64*)(lds_src);
  u64 hi = *(const u64*)(lds_src + 4);
  __hip_atomic_store((u64*)p, lo, __ATOMIC_RELAXED, __HIP_MEMORY_SCOPE_AGENT);
  __hip_atomic_store((u64*)p + 1, hi, __ATOMIC_RELAXED, __HIP_MEMORY_SCOPE_AGENT);
}
__device__ __forceinline__ void waitflag(const unsigned int* p, unsigned int target) {
  while (__hip_atomic_load(p, __ATOMIC_RELAXED, __HIP_MEMORY_SCOPE_AGENT) < target)
    __builtin_amdgcn_s_sleep(1);
}

// ---------------- pack x: f32 [B*T][264] -> bf16 [B*T][256] ----------------
__global__ __launch_bounds__(256) void pack_x_k(const float* __restrict__ x,
                                                bf16* __restrict__ xbf) {
  const long idx = ((long)blockIdx.x * 256 + threadIdx.x) * 4;
  const long row = idx >> 8;
  const int f = (int)(idx & 255);
  const float4 v = *(const float4*)(x + row * 264 + f);
  bf16* p = xbf + row * 256 + f;
  p[0] = __float2bfloat16(v.x);
  p[1] = __float2bfloat16(v.y);
  p[2] = __float2bfloat16(v.z);
  p[3] = __float2bfloat16(v.w);
}

// ---------------- transpose+cast: WT[n][k] = bf16(W[k][n]) ----------------
__global__ __launch_bounds__(256) void transpose_k(const float* __restrict__ W,
                                                   bf16* __restrict__ WT,
                                                   int K, int N) {
  __shared__ bf16 tile[32][33];
  const int n0 = blockIdx.x * 32, k0 = blockIdx.y * 32;
  const int c = threadIdx.x & 31, r0 = threadIdx.x >> 5;
  for (int i = 0; i < 4; ++i) {
    int r = r0 + 8 * i;
    tile[r][c] = __float2bfloat16(W[(long)(k0 + r) * N + (n0 + c)]);
  }
  __syncthreads();
  for (int i = 0; i < 4; ++i) {
    int r = r0 + 8 * i;
    WT[(long)(n0 + r) * K + (k0 + c)] = tile[c][r];
  }
}

// ---------------- fused 2-layer persistent LSTM, wavefront-pipelined --------
// 128 WGs x 256 thr. layer = blk>>6, w = blk&63 owns h-cols [8w,8w+8).
// h history hseq[t][b][512] (write-once addresses). Per-WG flag words
// (64B apart) replace the shared atomic counter; flags polled one-per-lane.
// All h traffic agent-scope; loads hoisted into register arrays so they
// pipeline (single vmcnt drain) instead of serializing per-MFMA.
__global__ __launch_bounds__(256, 1) void lstm2_fused_k(
    const bf16* __restrict__ xbf,
    const bf16* __restrict__ WiT0, const bf16* __restrict__ WhT0,
    const float* __restrict__ bias0,
    const bf16* __restrict__ WiT1, const bf16* __restrict__ WhT1,
    const float* __restrict__ bias1,
    bf16* __restrict__ h1seq, bf16* __restrict__ h2seq,
    unsigned int* __restrict__ flags)  // [2][64] stride-16 u32, zeroed
{
  __shared__ short Wis[32 * 520];
  __shared__ short Whs[32 * 520];
  __shared__ float zs[32 * 66];
  __shared__ bf16 hstage[64 * 8];

  const int layer = blockIdx.x >> 6;
  const int w = blockIdx.x & 63;
  const int tid = threadIdx.x;
  const int lane = tid & 63;
  const int wv = tid >> 6;
  const int q = lane >> 4;
  const int r = lane & 15;

  const int K_in = layer ? 512 : 256;
  const bf16* WiT = layer ? WiT1 : WiT0;
  const bf16* WhT = layer ? WhT1 : WhT0;
  const float* bias = layer ? bias1 : bias0;
  const bf16* hprevseq = layer ? h2seq : h1seq;
  bf16* hout = layer ? h2seq : h1seq;
  unsigned int* flags0 = flags;              // layer-0 per-WG step counters
  unsigned int* flags1 = flags + 64 * 16;    // layer-1 per-WG step counters
  unsigned int* myflag = (layer ? flags1 : flags0) + w * 16;

  // ---- stage weight slices into LDS (reused all 512 steps) ----
  for (int idx = tid; idx < 32 * 64; idx += 256) {
    const int j = idx >> 6, kc = idx & 63;
    const int zc = (j >> 3) * 512 + w * 8 + (j & 7);
    *(bf16x8*)(Whs + j * 520 + kc * 8) = *(const bf16x8*)(WhT + (long)zc * 512 + kc * 8);
  }
  const int csh = layer ? 6 : 5;
  const int cmask = (1 << csh) - 1;
  for (int idx = tid; idx < (32 << csh); idx += 256) {
    const int j = idx >> csh, kc = idx & cmask;
    const int zc = (j >> 3) * 512 + w * 8 + (j & 7);
    *(bf16x8*)(Wis + j * 520 + kc * 8) = *(const bf16x8*)(WiT + (long)zc * K_in + kc * 8);
  }

  const int m = wv * 16 + r;
  const short* wi0p = Wis + r * 520;
  const short* wi1p = Wis + (16 + r) * 520;
  const short* wh0p = Whs + r * 520;
  const short* wh1p = Whs + (16 + r) * 520;

  const int gb = tid & 63;
  const int gc0 = tid >> 6;
  float bias_r[2][4];
  for (int s = 0; s < 2; ++s)
    for (int g = 0; g < 4; ++g)
      bias_r[s][g] = bias[g * 512 + w * 8 + gc0 + 4 * s];
  float creg[2] = {0.f, 0.f};

  __syncthreads();

  for (int t = 0; t < 512; ++t) {
    f32x4 acc0 = {0.f, 0.f, 0.f, 0.f};
    f32x4 acc1 = {0.f, 0.f, 0.f, 0.f};

    if (layer == 0) {
      // x-part loads issued BEFORE the wait (plain cached, independent of h)
      const bf16* arow = xbf + ((long)m * 512 + t) * 256;
      bf16x8 ax[8];
#pragma unroll
      for (int i = 0; i < 8; ++i) ax[i] = *(const bf16x8*)(arow + i * 32 + q * 8);

      if (t > 0 && tid < 64) waitflag(flags0 + tid * 16, (unsigned)t);
      __syncthreads();

      bf16x8 ah[16];
      if (t > 0) {
        const bf16* hrow = hprevseq + ((long)(t - 1) * 64 + m) * 512;
#pragma unroll
        for (int i = 0; i < 16; ++i) ah[i] = ld_h16(hrow + i * 32 + q * 8);
      }
#pragma unroll
      for (int i = 0; i < 8; ++i) {
        const int kk = i * 32;
        acc0 = MFMA16(ax[i], *(const bf16x8*)(wi0p + kk + q * 8), acc0);
        acc1 = MFMA16(ax[i], *(const bf16x8*)(wi1p + kk + q * 8), acc1);
      }
      if (t > 0) {
#pragma unroll
        for (int i = 0; i < 16; ++i) {
          const int kk = i * 32;
          acc0 = MFMA16(ah[i], *(const bf16x8*)(wh0p + kk + q * 8), acc0);
          acc1 = MFMA16(ah[i], *(const bf16x8*)(wh1p + kk + q * 8), acc1);
        }
      }
    } else {
      if (tid < 64) waitflag(flags0 + tid * 16, (unsigned)(t + 1));       // h1[t]
      else if (tid < 128 && t > 0) waitflag(flags1 + (tid - 64) * 16, (unsigned)t);
      __syncthreads();

      bf16x8 ax[16];
      {
        const bf16* arow = h1seq + ((long)t * 64 + m) * 512;
#pragma unroll
        for (int i = 0; i < 16; ++i) ax[i] = ld_h16(arow + i * 32 + q * 8);
      }
      bf16x8 ah[16];
      if (t > 0) {
        const bf16* hrow = hprevseq + ((long)(t - 1) * 64 + m) * 512;
#pragma unroll
        for (int i = 0; i < 16; ++i) ah[i] = ld_h16(hrow + i * 32 + q * 8);
      }
#pragma unroll
      for (int i = 0; i < 16; ++i) {
        const int kk = i * 32;
        acc0 = MFMA16(ax[i], *(const bf16x8*)(wi0p + kk + q * 8), acc0);
        acc1 = MFMA16(ax[i], *(const bf16x8*)(wi1p + kk + q * 8), acc1);
      }
      if (t > 0) {
#pragma unroll
        for (int i = 0; i < 16; ++i) {
          const int kk = i * 32;
          acc0 = MFMA16(ah[i], *(const bf16x8*)(wh0p + kk + q * 8), acc0);
          acc1 = MFMA16(ah[i], *(const bf16x8*)(wh1p + kk + q * 8), acc1);
        }
      }
    }

    // D-layout: row(b)=wv*16+q*4+i, col(n)=ntile*16+r  [m89-verified]
    {
      const int brow = wv * 16 + q * 4;
      for (int i = 0; i < 4; ++i) zs[r * 66 + brow + i] = acc0[i];
      for (int i = 0; i < 4; ++i) zs[(16 + r) * 66 + brow + i] = acc1[i];
    }
    __syncthreads();

    for (int s = 0; s < 2; ++s) {
      const int c = gc0 + 4 * s;
      const float zi = zs[(c)*66 + gb] + bias_r[s][0];
      const float zf = zs[(8 + c) * 66 + gb] + bias_r[s][1];
      const float zg = zs[(16 + c) * 66 + gb] + bias_r[s][2];
      const float zo = zs[(24 + c) * 66 + gb] + bias_r[s][3];
      const float cnew = sigf(zf) * creg[s] + sigf(zi) * tanh_fast(zg);
      const float hnew = sigf(zo) * tanh_fast(cnew);
      creg[s] = cnew;
      hstage[gb * 8 + c] = __float2bfloat16(hnew);
    }
    __syncthreads();

    if (tid < 64) st_h16(hout + ((long)t * 64 + tid) * 512 + w * 8, hstage + tid * 8);
    __syncthreads();  // barrier drains vmcnt(0): h stores visible before flag
    if (tid == 0)
      __hip_atomic_store(myflag, (unsigned)(t + 1), __ATOMIC_RELAXED, __HIP_MEMORY_SCOPE_AGENT);
  }
}

// ---------------- dense head: concat -> 512 -> 256 -> 64 -> sigmoid ----------
__global__ __launch_bounds__(256) void head_k(
    const bf16* __restrict__ hlast,
    const float* __restrict__ x,
    const float* __restrict__ Wd0, const float* __restrict__ bd0,
    const float* __restrict__ Wd1, const float* __restrict__ bd1,
    const float* __restrict__ Wf, const float* __restrict__ bfv,
    float* __restrict__ out) {
  const int b = blockIdx.x, tid = threadIdx.x;
  __shared__ float in0[520];
  __shared__ float d0s[512];
  __shared__ float d1s[256];
  for (int k = tid; k < 512; k += 256) in0[k] = __bfloat162float(hlast[b * 512 + k]);
  if (tid < 8) in0[512 + tid] = x[((long)(b * 512 + 511)) * 264 + 256 + tid];
  __syncthreads();
  for (int j = tid; j < 512; j += 256) {
    float a = bd0[j];
    for (int k = 0; k < 520; ++k) a += in0[k] * Wd0[(long)k * 512 + j];
    d0s[j] = fmaxf(a, 0.f);
  }
  __syncthreads();
  if (tid < 256) {
    const int j = tid;
    float a = bd1[j];
    for (int k = 0; k < 512; ++k) a += d0s[k] * Wd1[(long)k * 256 + j];
    d1s[j] = fmaxf(a, 0.f);
  }
  __syncthreads();
  if (tid < 64) {
    const int j = tid;
    float a = bfv[j];
    for (int k = 0; k < 256; ++k) a += d1s[k] * Wf[(long)k * 64 + j];
    out[b * 64 + j] = sigf(a);
  }
}

extern "C" void kernel_launch(void* const* d_in, const int* in_sizes, int n_in,
                              void* d_out, int out_size, void* d_ws, size_t ws_size,
                              hipStream_t stream) {
  const float* x   = (const float*)d_in[0];
  const float* Wi0 = (const float*)d_in[1];
  const float* Wh0 = (const float*)d_in[2];
  const float* b0  = (const float*)d_in[3];
  const float* Wi1 = (const float*)d_in[4];
  const float* Wh1 = (const float*)d_in[5];
  const float* b1  = (const float*)d_in[6];
  const float* Wd0 = (const float*)d_in[7];
  const float* bd0 = (const float*)d_in[8];
  const float* Wd1 = (const float*)d_in[9];
  const float* bd1 = (const float*)d_in[10];
  const float* Wf  = (const float*)d_in[11];
  const float* bf_ = (const float*)d_in[12];
  float* out = (float*)d_out;

  char* ws = (char*)d_ws;
  size_t off = 0;
  auto carve = [&](size_t bytes) {
    void* p = ws + off;
    off += (bytes + 255) & ~(size_t)255;
    return p;
  };
  unsigned int* flags = (unsigned int*)carve(2 * 64 * 16 * sizeof(unsigned int));
  const size_t zero_bytes = off;
  bf16* xbf  = (bf16*)carve((size_t)64 * 512 * 256 * 2);
  bf16* WiT0 = (bf16*)carve((size_t)2048 * 256 * 2);
  bf16* WhT0 = (bf16*)carve((size_t)2048 * 512 * 2);
  bf16* WiT1 = (bf16*)carve((size_t)2048 * 512 * 2);
  bf16* WhT1 = (bf16*)carve((size_t)2048 * 512 * 2);
  bf16* h1seq = (bf16*)carve((size_t)512 * 64 * 512 * 2);
  bf16* h2seq = (bf16*)carve((size_t)512 * 64 * 512 * 2);

  hipMemsetAsync(d_ws, 0, zero_bytes, stream);

  pack_x_k<<<8192, 256, 0, stream>>>(x, xbf);
  transpose_k<<<dim3(2048 / 32, 256 / 32), 256, 0, stream>>>(Wi0, WiT0, 256, 2048);
  transpose_k<<<dim3(2048 / 32, 512 / 32), 256, 0, stream>>>(Wh0, WhT0, 512, 2048);
  transpose_k<<<dim3(2048 / 32, 512 / 32), 256, 0, stream>>>(Wi1, WiT1, 512, 2048);
  transpose_k<<<dim3(2048 / 32, 512 / 32), 256, 0, stream>>>(Wh1, WhT1, 512, 2048);

  lstm2_fused_k<<<128, 256, 0, stream>>>(xbf, WiT0, WhT0, b0, WiT1, WhT1, b1,
                                         h1seq, h2seq, flags);

  head_k<<<64, 256, 0, stream>>>(h2seq + (size_t)511 * 64 * 512, x,
                                 Wd0, bd0, Wd1, bd1, Wf, bf_, out);
}

// Round 5
// 4930.836 us; speedup vs baseline: 1.1552x; 1.1552x over previous
//
#include <hip/hip_runtime.h>
#include <hip/hip_bf16.h>

typedef __hip_bfloat16 bf16;
typedef short bf16x8 __attribute__((ext_vector_type(8)));
typedef float f32x4 __attribute__((ext_vector_type(4)));
typedef unsigned long long u64;
typedef unsigned int u32;

#define MFMA16(A, B, C) __builtin_amdgcn_mfma_f32_16x16x32_bf16(A, B, C, 0, 0, 0)

__device__ __forceinline__ float sigf(float x) { return 1.f / (1.f + __expf(-x)); }
__device__ __forceinline__ float tanh_fast(float x) { return 2.f / (1.f + __expf(-2.f * x)) - 1.f; }

// ---------------- transpose+cast: WT[n][k] = bf16(W[k][n]) ----------------
__global__ __launch_bounds__(256) void transpose_k(const float* __restrict__ W,
                                                   bf16* __restrict__ WT,
                                                   int K, int N) {
  __shared__ bf16 tile[32][33];
  const int n0 = blockIdx.x * 32, k0 = blockIdx.y * 32;
  const int c = threadIdx.x & 31, r0 = threadIdx.x >> 5;
  for (int i = 0; i < 4; ++i) {
    int r = r0 + 8 * i;
    tile[r][c] = __float2bfloat16(W[(long)(k0 + r) * N + (n0 + c)]);
  }
  __syncthreads();
  for (int i = 0; i < 4; ++i) {
    int r = r0 + 8 * i;
    WT[(long)(n0 + r) * K + (k0 + c)] = tile[c][r];
  }
}

// Tagged-h matrix for one timestep: [64 slices][64 rows][8 u32], u32 = (h<<16)|tag.
// gather16: per-lane fetch of 16 k-chunks (slices i*4+q), self-validating poll.
__device__ __forceinline__ void gather16(const u64* __restrict__ mat, int m, int q,
                                         unsigned tag, bf16x8* out) {
  const u64 want = ((u64)tag) | ((u64)tag << 32);
#pragma unroll
  for (int h = 0; h < 2; ++h) {
    const u64* pp[8];
    u64 v[8][4];
#pragma unroll
    for (int i = 0; i < 8; ++i) {
      const int slice = (h * 8 + i) * 4 + q;
      pp[i] = mat + ((long)slice * 64 + m) * 4;
#pragma unroll
      for (int j = 0; j < 4; ++j)
        v[i][j] = __hip_atomic_load(pp[i] + j, __ATOMIC_RELAXED, __HIP_MEMORY_SCOPE_AGENT);
    }
    for (;;) {
      u64 bad = 0;
#pragma unroll
      for (int i = 0; i < 8; ++i)
#pragma unroll
        for (int j = 0; j < 4; ++j)
          bad |= (v[i][j] ^ want) & 0x0000ffff0000ffffULL;
      if (bad == 0) break;
      __builtin_amdgcn_s_sleep(1);
#pragma unroll
      for (int i = 0; i < 8; ++i)
#pragma unroll
        for (int j = 0; j < 4; ++j)
          v[i][j] = __hip_atomic_load(pp[i] + j, __ATOMIC_RELAXED, __HIP_MEMORY_SCOPE_AGENT);
    }
#pragma unroll
    for (int i = 0; i < 8; ++i) {
      union { u32 u[4]; bf16x8 v8; } o;
#pragma unroll
      for (int j = 0; j < 4; ++j) {
        u32 lo = (u32)v[i][j];
        u32 hi = (u32)(v[i][j] >> 32);
        o.u[j] = (lo >> 16) | (hi & 0xffff0000u);  // 2 bf16 payloads
      }
      out[h * 8 + i] = o.v8;
    }
  }
}

// ---------------- fused 2-layer persistent LSTM, tagged-dataflow ------------
// 128 WGs x 256 thr. layer = blk>>6, w = blk&63 owns h-cols [8w,8w+8).
// No flags, no fences, no store drains: validity rides in the data words.
// h1T: [512][64 slices][64 rows][8] u32 (full history; layer-1 consumes).
// h2T: ring [4][64][64][8] u32 (layer-1 self-recurrence; tags disambiguate).
__global__ __launch_bounds__(256, 1) void lstm2_fused_k(
    const float* __restrict__ x,  // [64][512][264] f32
    const bf16* __restrict__ WiT0, const bf16* __restrict__ WhT0,
    const float* __restrict__ bias0,
    const bf16* __restrict__ WiT1, const bf16* __restrict__ WhT1,
    const float* __restrict__ bias1,
    u64* __restrict__ h1T, u64* __restrict__ h2T)
{
  __shared__ short Wis[32 * 520];
  __shared__ short Whs[32 * 520];
  __shared__ float zs[32 * 66];
  __shared__ __align__(16) u32 hstage[64 * 8];

  const int layer = blockIdx.x >> 6;
  const int w = blockIdx.x & 63;
  const int tid = threadIdx.x;
  const int lane = tid & 63;
  const int wv = tid >> 6;
  const int q = lane >> 4;
  const int r = lane & 15;

  const int K_in = layer ? 512 : 256;
  const bf16* WiT = layer ? WiT1 : WiT0;
  const bf16* WhT = layer ? WhT1 : WhT0;
  const float* bias = layer ? bias1 : bias0;

  // ---- stage weight slices into LDS (reused all 512 steps) ----
  for (int idx = tid; idx < 32 * 64; idx += 256) {
    const int j = idx >> 6, kc = idx & 63;
    const int zc = (j >> 3) * 512 + w * 8 + (j & 7);
    *(bf16x8*)(Whs + j * 520 + kc * 8) = *(const bf16x8*)(WhT + (long)zc * 512 + kc * 8);
  }
  const int csh = layer ? 6 : 5;
  const int cmask = (1 << csh) - 1;
  for (int idx = tid; idx < (32 << csh); idx += 256) {
    const int j = idx >> csh, kc = idx & cmask;
    const int zc = (j >> 3) * 512 + w * 8 + (j & 7);
    *(bf16x8*)(Wis + j * 520 + kc * 8) = *(const bf16x8*)(WiT + (long)zc * K_in + kc * 8);
  }

  const int m = wv * 16 + r;
  const short* wi0p = Wis + r * 520;
  const short* wi1p = Wis + (16 + r) * 520;
  const short* wh0p = Whs + r * 520;
  const short* wh1p = Whs + (16 + r) * 520;

  const int gb = tid & 63;
  const int gc0 = tid >> 6;
  float bias_r[2][4];
  for (int s = 0; s < 2; ++s)
    for (int g = 0; g < 4; ++g)
      bias_r[s][g] = bias[g * 512 + w * 8 + gc0 + 4 * s];
  float creg[2] = {0.f, 0.f};

  __syncthreads();

  for (int t = 0; t < 512; ++t) {
    f32x4 acc0 = {0.f, 0.f, 0.f, 0.f};
    f32x4 acc1 = {0.f, 0.f, 0.f, 0.f};

    if (layer == 0) {
      // x-part: direct f32 loads + convert (independent of any producer)
      bf16x8 ax[8];
      const float* row = x + ((long)m * 512 + t) * 264;
#pragma unroll
      for (int i = 0; i < 8; ++i) {
        const float4 f0 = *(const float4*)(row + i * 32 + q * 8);
        const float4 f1 = *(const float4*)(row + i * 32 + q * 8 + 4);
        union { short s[8]; bf16x8 v8; } o;
        o.s[0] = __builtin_bit_cast(short, __float2bfloat16(f0.x));
        o.s[1] = __builtin_bit_cast(short, __float2bfloat16(f0.y));
        o.s[2] = __builtin_bit_cast(short, __float2bfloat16(f0.z));
        o.s[3] = __builtin_bit_cast(short, __float2bfloat16(f0.w));
        o.s[4] = __builtin_bit_cast(short, __float2bfloat16(f1.x));
        o.s[5] = __builtin_bit_cast(short, __float2bfloat16(f1.y));
        o.s[6] = __builtin_bit_cast(short, __float2bfloat16(f1.z));
        o.s[7] = __builtin_bit_cast(short, __float2bfloat16(f1.w));
        ax[i] = o.v8;
      }
#pragma unroll
      for (int i = 0; i < 8; ++i) {
        const int kk = i * 32;
        acc0 = MFMA16(ax[i], *(const bf16x8*)(wi0p + kk + q * 8), acc0);
        acc1 = MFMA16(ax[i], *(const bf16x8*)(wi1p + kk + q * 8), acc1);
      }
      if (t > 0) {
        bf16x8 ah[16];
        gather16(h1T + (long)(t - 1) * 16384, m, q, (unsigned)t, ah);
#pragma unroll
        for (int i = 0; i < 16; ++i) {
          const int kk = i * 32;
          acc0 = MFMA16(ah[i], *(const bf16x8*)(wh0p + kk + q * 8), acc0);
          acc1 = MFMA16(ah[i], *(const bf16x8*)(wh1p + kk + q * 8), acc1);
        }
      }
    } else {
      // x-part = h1[t] (tag t+1)
      bf16x8 ax[16];
      gather16(h1T + (long)t * 16384, m, q, (unsigned)(t + 1), ax);
#pragma unroll
      for (int i = 0; i < 16; ++i) {
        const int kk = i * 32;
        acc0 = MFMA16(ax[i], *(const bf16x8*)(wi0p + kk + q * 8), acc0);
        acc1 = MFMA16(ax[i], *(const bf16x8*)(wi1p + kk + q * 8), acc1);
      }
      if (t > 0) {
        bf16x8 ah[16];
        gather16(h2T + (long)((t - 1) & 3) * 16384, m, q, (unsigned)t, ah);
#pragma unroll
        for (int i = 0; i < 16; ++i) {
          const int kk = i * 32;
          acc0 = MFMA16(ah[i], *(const bf16x8*)(wh0p + kk + q * 8), acc0);
          acc1 = MFMA16(ah[i], *(const bf16x8*)(wh1p + kk + q * 8), acc1);
        }
      }
    }

    // D-layout: row(b)=wv*16+q*4+i, col(n)=ntile*16+r  [m89-verified]
    {
      const int brow = wv * 16 + q * 4;
      for (int i = 0; i < 4; ++i) zs[r * 66 + brow + i] = acc0[i];
      for (int i = 0; i < 4; ++i) zs[(16 + r) * 66 + brow + i] = acc1[i];
    }
    __syncthreads();

    // gates -> tagged h words in hstage
    for (int s = 0; s < 2; ++s) {
      const int c = gc0 + 4 * s;
      const float zi = zs[(c)*66 + gb] + bias_r[s][0];
      const float zf = zs[(8 + c) * 66 + gb] + bias_r[s][1];
      const float zg = zs[(16 + c) * 66 + gb] + bias_r[s][2];
      const float zo = zs[(24 + c) * 66 + gb] + bias_r[s][3];
      const float cnew = sigf(zf) * creg[s] + sigf(zi) * tanh_fast(zg);
      const float hnew = sigf(zo) * tanh_fast(cnew);
      creg[s] = cnew;
      const unsigned short hb = __builtin_bit_cast(unsigned short, __float2bfloat16(hnew));
      hstage[gb * 8 + c] = ((u32)hb << 16) | (u32)(t + 1);
    }
    __syncthreads();

    // publish slice: one coalesced 2KB burst (fire-and-forget, no drain)
    {
      u64* outbase = (layer ? h2T + (long)(t & 3) * 16384 : h1T + (long)t * 16384) + (long)w * 256;
      if (tid < 128) {
        const int b = tid >> 1, half = tid & 1;
        const u32* src = hstage + b * 8 + half * 4;
        u64 lo = *(const u64*)(src);
        u64 hi = *(const u64*)(src + 2);
        u64* dst = outbase + (long)b * 4 + half * 2;
        __hip_atomic_store(dst, lo, __ATOMIC_RELAXED, __HIP_MEMORY_SCOPE_AGENT);
        __hip_atomic_store(dst + 1, hi, __ATOMIC_RELAXED, __HIP_MEMORY_SCOPE_AGENT);
      }
    }
  }
}

// ---------------- dense head: concat -> 512 -> 256 -> 64 -> sigmoid ----------
__global__ __launch_bounds__(256) void head_k(
    const u32* __restrict__ h2ring,  // tagged ring; slot 3 holds t=511
    const float* __restrict__ x,
    const float* __restrict__ Wd0, const float* __restrict__ bd0,
    const float* __restrict__ Wd1, const float* __restrict__ bd1,
    const float* __restrict__ Wf, const float* __restrict__ bfv,
    float* __restrict__ out) {
  const int b = blockIdx.x, tid = threadIdx.x;
  __shared__ float in0[520];
  __shared__ float d0s[512];
  __shared__ float d1s[256];
  for (int k = tid; k < 512; k += 256) {
    const int slice = k >> 3;
    const u32 uv = h2ring[(((long)3 * 64 + slice) * 64 + b) * 8 + (k & 7)];
    const unsigned short hb = (unsigned short)(uv >> 16);
    in0[k] = __bfloat162float(__builtin_bit_cast(bf16, hb));
  }
  if (tid < 8) in0[512 + tid] = x[((long)(b * 512 + 511)) * 264 + 256 + tid];
  __syncthreads();
  for (int j = tid; j < 512; j += 256) {
    float a = bd0[j];
    for (int k = 0; k < 520; ++k) a += in0[k] * Wd0[(long)k * 512 + j];
    d0s[j] = fmaxf(a, 0.f);
  }
  __syncthreads();
  if (tid < 256) {
    const int j = tid;
    float a = bd1[j];
    for (int k = 0; k < 512; ++k) a += d0s[k] * Wd1[(long)k * 256 + j];
    d1s[j] = fmaxf(a, 0.f);
  }
  __syncthreads();
  if (tid < 64) {
    const int j = tid;
    float a = bfv[j];
    for (int k = 0; k < 256; ++k) a += d1s[k] * Wf[(long)k * 64 + j];
    out[b * 64 + j] = sigf(a);
  }
}

extern "C" void kernel_launch(void* const* d_in, const int* in_sizes, int n_in,
                              void* d_out, int out_size, void* d_ws, size_t ws_size,
                              hipStream_t stream) {
  const float* x   = (const float*)d_in[0];
  const float* Wi0 = (const float*)d_in[1];
  const float* Wh0 = (const float*)d_in[2];
  const float* b0  = (const float*)d_in[3];
  const float* Wi1 = (const float*)d_in[4];
  const float* Wh1 = (const float*)d_in[5];
  const float* b1  = (const float*)d_in[6];
  const float* Wd0 = (const float*)d_in[7];
  const float* bd0 = (const float*)d_in[8];
  const float* Wd1 = (const float*)d_in[9];
  const float* bd1 = (const float*)d_in[10];
  const float* Wf  = (const float*)d_in[11];
  const float* bf_ = (const float*)d_in[12];
  float* out = (float*)d_out;

  char* ws = (char*)d_ws;
  size_t off = 0;
  auto carve = [&](size_t bytes) {
    void* p = ws + off;
    off += (bytes + 255) & ~(size_t)255;
    return p;
  };
  bf16* WiT0 = (bf16*)carve((size_t)2048 * 256 * 2);
  bf16* WhT0 = (bf16*)carve((size_t)2048 * 512 * 2);
  bf16* WiT1 = (bf16*)carve((size_t)2048 * 512 * 2);
  bf16* WhT1 = (bf16*)carve((size_t)2048 * 512 * 2);
  u64*  h1T  = (u64*)carve((size_t)512 * 64 * 64 * 32);  // 64 MB tagged history
  u64*  h2T  = (u64*)carve((size_t)4 * 64 * 64 * 32);    // 512 KB tagged ring

  // invalidate all tags (tag 0 never matches t+1 >= 1)
  hipMemsetAsync(h1T, 0, (size_t)512 * 64 * 64 * 32, stream);
  hipMemsetAsync(h2T, 0, (size_t)4 * 64 * 64 * 32, stream);

  transpose_k<<<dim3(2048 / 32, 256 / 32), 256, 0, stream>>>(Wi0, WiT0, 256, 2048);
  transpose_k<<<dim3(2048 / 32, 512 / 32), 256, 0, stream>>>(Wh0, WhT0, 512, 2048);
  transpose_k<<<dim3(2048 / 32, 512 / 32), 256, 0, stream>>>(Wi1, WiT1, 512, 2048);
  transpose_k<<<dim3(2048 / 32, 512 / 32), 256, 0, stream>>>(Wh1, WhT1, 512, 2048);

  lstm2_fused_k<<<128, 256, 0, stream>>>(x, WiT0, WhT0, b0, WiT1, WhT1, b1, h1T, h2T);

  head_k<<<64, 256, 0, stream>>>((const u32*)h2T, x, Wd0, bd0, Wd1, bd1, Wf, bf_, out);
}

// Round 6
// 4923.021 us; speedup vs baseline: 1.1570x; 1.0016x over previous
//
#include <hip/hip_runtime.h>
#include <hip/hip_bf16.h>

typedef __hip_bfloat16 bf16;
typedef short bf16x8 __attribute__((ext_vector_type(8)));
typedef float f32x4 __attribute__((ext_vector_type(4)));
typedef unsigned long long u64;
typedef unsigned int u32;

#define MFMA16(A, B, C) __builtin_amdgcn_mfma_f32_16x16x32_bf16(A, B, C, 0, 0, 0)

__device__ __forceinline__ float sigf(float x) { return 1.f / (1.f + __expf(-x)); }
__device__ __forceinline__ float tanh_fast(float x) { return 2.f / (1.f + __expf(-2.f * x)) - 1.f; }

// ---------------- transpose+cast: WT[n][k] = bf16(W[k][n]) ----------------
__global__ __launch_bounds__(256) void transpose_k(const float* __restrict__ W,
                                                   bf16* __restrict__ WT,
                                                   int K, int N) {
  __shared__ bf16 tile[32][33];
  const int n0 = blockIdx.x * 32, k0 = blockIdx.y * 32;
  const int c = threadIdx.x & 31, r0 = threadIdx.x >> 5;
  for (int i = 0; i < 4; ++i) {
    int r = r0 + 8 * i;
    tile[r][c] = __float2bfloat16(W[(long)(k0 + r) * N + (n0 + c)]);
  }
  __syncthreads();
  for (int i = 0; i < 4; ++i) {
    int r = r0 + 8 * i;
    WT[(long)(n0 + r) * K + (k0 + c)] = tile[c][r];
  }
}

// Tagged-h matrix for one timestep: [64 slices][64 rows][8 u32], u32 = (h<<16)|tag.
// SYSTEM scope => sc0 sc1 (bypass L1 AND L2): loads always reach the MALL
// coherence point, so fresh producer data is observed in ~1 fabric round-trip
// instead of waiting for L2-line eviction (the r2-r5 ~10us/step failure mode).
__device__ __forceinline__ void gather16(const u64* __restrict__ mat, int m, int q,
                                         unsigned tag, bf16x8* out) {
  const u64 want = ((u64)tag) | ((u64)tag << 32);
#pragma unroll
  for (int h = 0; h < 2; ++h) {
    const u64* pp[8];
    u64 v[8][4];
#pragma unroll
    for (int i = 0; i < 8; ++i) {
      const int slice = (h * 8 + i) * 4 + q;
      pp[i] = mat + ((long)slice * 64 + m) * 4;
#pragma unroll
      for (int j = 0; j < 4; ++j)
        v[i][j] = __hip_atomic_load(pp[i] + j, __ATOMIC_RELAXED, __HIP_MEMORY_SCOPE_SYSTEM);
    }
    for (;;) {
      u64 bad = 0;
#pragma unroll
      for (int i = 0; i < 8; ++i)
#pragma unroll
        for (int j = 0; j < 4; ++j)
          bad |= (v[i][j] ^ want) & 0x0000ffff0000ffffULL;
      if (bad == 0) break;
      __builtin_amdgcn_s_sleep(1);
#pragma unroll
      for (int i = 0; i < 8; ++i)
#pragma unroll
        for (int j = 0; j < 4; ++j)
          v[i][j] = __hip_atomic_load(pp[i] + j, __ATOMIC_RELAXED, __HIP_MEMORY_SCOPE_SYSTEM);
    }
#pragma unroll
    for (int i = 0; i < 8; ++i) {
      union { u32 u[4]; bf16x8 v8; } o;
#pragma unroll
      for (int j = 0; j < 4; ++j) {
        u32 lo = (u32)v[i][j];
        u32 hi = (u32)(v[i][j] >> 32);
        o.u[j] = (lo >> 16) | (hi & 0xffff0000u);  // 2 bf16 payloads
      }
      out[h * 8 + i] = o.v8;
    }
  }
}

// ---------------- fused 2-layer persistent LSTM, tagged-dataflow ------------
// 128 WGs x 256 thr. layer = blk>>6, w = blk&63 owns h-cols [8w,8w+8).
// No flags, no fences, no store drains: validity rides in the data words.
// h1T: [512][64 slices][64 rows][8] u32 (full history; layer-1 consumes).
// h2T: ring [4][64][64][8] u32 (layer-1 self-recurrence; tags disambiguate).
__global__ __launch_bounds__(256, 1) void lstm2_fused_k(
    const float* __restrict__ x,  // [64][512][264] f32
    const bf16* __restrict__ WiT0, const bf16* __restrict__ WhT0,
    const float* __restrict__ bias0,
    const bf16* __restrict__ WiT1, const bf16* __restrict__ WhT1,
    const float* __restrict__ bias1,
    u64* __restrict__ h1T, u64* __restrict__ h2T)
{
  __shared__ short Wis[32 * 520];
  __shared__ short Whs[32 * 520];
  __shared__ float zs[32 * 66];
  __shared__ __align__(16) u32 hstage[64 * 8];

  const int layer = blockIdx.x >> 6;
  const int w = blockIdx.x & 63;
  const int tid = threadIdx.x;
  const int lane = tid & 63;
  const int wv = tid >> 6;
  const int q = lane >> 4;
  const int r = lane & 15;

  const int K_in = layer ? 512 : 256;
  const bf16* WiT = layer ? WiT1 : WiT0;
  const bf16* WhT = layer ? WhT1 : WhT0;
  const float* bias = layer ? bias1 : bias0;

  // ---- stage weight slices into LDS (reused all 512 steps) ----
  for (int idx = tid; idx < 32 * 64; idx += 256) {
    const int j = idx >> 6, kc = idx & 63;
    const int zc = (j >> 3) * 512 + w * 8 + (j & 7);
    *(bf16x8*)(Whs + j * 520 + kc * 8) = *(const bf16x8*)(WhT + (long)zc * 512 + kc * 8);
  }
  const int csh = layer ? 6 : 5;
  const int cmask = (1 << csh) - 1;
  for (int idx = tid; idx < (32 << csh); idx += 256) {
    const int j = idx >> csh, kc = idx & cmask;
    const int zc = (j >> 3) * 512 + w * 8 + (j & 7);
    *(bf16x8*)(Wis + j * 520 + kc * 8) = *(const bf16x8*)(WiT + (long)zc * K_in + kc * 8);
  }

  const int m = wv * 16 + r;
  const short* wi0p = Wis + r * 520;
  const short* wi1p = Wis + (16 + r) * 520;
  const short* wh0p = Whs + r * 520;
  const short* wh1p = Whs + (16 + r) * 520;

  const int gb = tid & 63;
  const int gc0 = tid >> 6;
  float bias_r[2][4];
  for (int s = 0; s < 2; ++s)
    for (int g = 0; g < 4; ++g)
      bias_r[s][g] = bias[g * 512 + w * 8 + gc0 + 4 * s];
  float creg[2] = {0.f, 0.f};

  __syncthreads();

  for (int t = 0; t < 512; ++t) {
    f32x4 acc0 = {0.f, 0.f, 0.f, 0.f};
    f32x4 acc1 = {0.f, 0.f, 0.f, 0.f};

    if (layer == 0) {
      // x-part: direct f32 loads + convert (independent of any producer)
      bf16x8 ax[8];
      const float* row = x + ((long)m * 512 + t) * 264;
#pragma unroll
      for (int i = 0; i < 8; ++i) {
        const float4 f0 = *(const float4*)(row + i * 32 + q * 8);
        const float4 f1 = *(const float4*)(row + i * 32 + q * 8 + 4);
        union { short s[8]; bf16x8 v8; } o;
        o.s[0] = __builtin_bit_cast(short, __float2bfloat16(f0.x));
        o.s[1] = __builtin_bit_cast(short, __float2bfloat16(f0.y));
        o.s[2] = __builtin_bit_cast(short, __float2bfloat16(f0.z));
        o.s[3] = __builtin_bit_cast(short, __float2bfloat16(f0.w));
        o.s[4] = __builtin_bit_cast(short, __float2bfloat16(f1.x));
        o.s[5] = __builtin_bit_cast(short, __float2bfloat16(f1.y));
        o.s[6] = __builtin_bit_cast(short, __float2bfloat16(f1.z));
        o.s[7] = __builtin_bit_cast(short, __float2bfloat16(f1.w));
        ax[i] = o.v8;
      }
#pragma unroll
      for (int i = 0; i < 8; ++i) {
        const int kk = i * 32;
        acc0 = MFMA16(ax[i], *(const bf16x8*)(wi0p + kk + q * 8), acc0);
        acc1 = MFMA16(ax[i], *(const bf16x8*)(wi1p + kk + q * 8), acc1);
      }
      if (t > 0) {
        bf16x8 ah[16];
        gather16(h1T + (long)(t - 1) * 16384, m, q, (unsigned)t, ah);
#pragma unroll
        for (int i = 0; i < 16; ++i) {
          const int kk = i * 32;
          acc0 = MFMA16(ah[i], *(const bf16x8*)(wh0p + kk + q * 8), acc0);
          acc1 = MFMA16(ah[i], *(const bf16x8*)(wh1p + kk + q * 8), acc1);
        }
      }
    } else {
      // x-part = h1[t] (tag t+1)
      bf16x8 ax[16];
      gather16(h1T + (long)t * 16384, m, q, (unsigned)(t + 1), ax);
#pragma unroll
      for (int i = 0; i < 16; ++i) {
        const int kk = i * 32;
        acc0 = MFMA16(ax[i], *(const bf16x8*)(wi0p + kk + q * 8), acc0);
        acc1 = MFMA16(ax[i], *(const bf16x8*)(wi1p + kk + q * 8), acc1);
      }
      if (t > 0) {
        bf16x8 ah[16];
        gather16(h2T + (long)((t - 1) & 3) * 16384, m, q, (unsigned)t, ah);
#pragma unroll
        for (int i = 0; i < 16; ++i) {
          const int kk = i * 32;
          acc0 = MFMA16(ah[i], *(const bf16x8*)(wh0p + kk + q * 8), acc0);
          acc1 = MFMA16(ah[i], *(const bf16x8*)(wh1p + kk + q * 8), acc1);
        }
      }
    }

    // D-layout: row(b)=wv*16+q*4+i, col(n)=ntile*16+r  [m89-verified]
    {
      const int brow = wv * 16 + q * 4;
      for (int i = 0; i < 4; ++i) zs[r * 66 + brow + i] = acc0[i];
      for (int i = 0; i < 4; ++i) zs[(16 + r) * 66 + brow + i] = acc1[i];
    }
    __syncthreads();

    // gates -> tagged h words in hstage
    for (int s = 0; s < 2; ++s) {
      const int c = gc0 + 4 * s;
      const float zi = zs[(c)*66 + gb] + bias_r[s][0];
      const float zf = zs[(8 + c) * 66 + gb] + bias_r[s][1];
      const float zg = zs[(16 + c) * 66 + gb] + bias_r[s][2];
      const float zo = zs[(24 + c) * 66 + gb] + bias_r[s][3];
      const float cnew = sigf(zf) * creg[s] + sigf(zi) * tanh_fast(zg);
      const float hnew = sigf(zo) * tanh_fast(cnew);
      creg[s] = cnew;
      const unsigned short hb = __builtin_bit_cast(unsigned short, __float2bfloat16(hnew));
      hstage[gb * 8 + c] = ((u32)hb << 16) | (u32)(t + 1);
    }
    __syncthreads();

    // publish slice: one coalesced 2KB burst, system scope (write-through to
    // the MALL coherence point; fire-and-forget, no drain)
    {
      u64* outbase = (layer ? h2T + (long)(t & 3) * 16384 : h1T + (long)t * 16384) + (long)w * 256;
      if (tid < 128) {
        const int b = tid >> 1, half = tid & 1;
        const u32* src = hstage + b * 8 + half * 4;
        u64 lo = *(const u64*)(src);
        u64 hi = *(const u64*)(src + 2);
        u64* dst = outbase + (long)b * 4 + half * 2;
        __hip_atomic_store(dst, lo, __ATOMIC_RELAXED, __HIP_MEMORY_SCOPE_SYSTEM);
        __hip_atomic_store(dst + 1, hi, __ATOMIC_RELAXED, __HIP_MEMORY_SCOPE_SYSTEM);
      }
    }
  }
}

// ---------------- dense head: concat -> 512 -> 256 -> 64 -> sigmoid ----------
__global__ __launch_bounds__(256) void head_k(
    const u32* __restrict__ h2ring,  // tagged ring; slot 3 holds t=511
    const float* __restrict__ x,
    const float* __restrict__ Wd0, const float* __restrict__ bd0,
    const float* __restrict__ Wd1, const float* __restrict__ bd1,
    const float* __restrict__ Wf, const float* __restrict__ bfv,
    float* __restrict__ out) {
  const int b = blockIdx.x, tid = threadIdx.x;
  __shared__ float in0[520];
  __shared__ float d0s[512];
  __shared__ float d1s[256];
  for (int k = tid; k < 512; k += 256) {
    const int slice = k >> 3;
    const u32 uv = h2ring[(((long)3 * 64 + slice) * 64 + b) * 8 + (k & 7)];
    const unsigned short hb = (unsigned short)(uv >> 16);
    in0[k] = __bfloat162float(__builtin_bit_cast(bf16, hb));
  }
  if (tid < 8) in0[512 + tid] = x[((long)(b * 512 + 511)) * 264 + 256 + tid];
  __syncthreads();
  for (int j = tid; j < 512; j += 256) {
    float a = bd0[j];
    for (int k = 0; k < 520; ++k) a += in0[k] * Wd0[(long)k * 512 + j];
    d0s[j] = fmaxf(a, 0.f);
  }
  __syncthreads();
  if (tid < 256) {
    const int j = tid;
    float a = bd1[j];
    for (int k = 0; k < 512; ++k) a += d0s[k] * Wd1[(long)k * 256 + j];
    d1s[j] = fmaxf(a, 0.f);
  }
  __syncthreads();
  if (tid < 64) {
    const int j = tid;
    float a = bfv[j];
    for (int k = 0; k < 256; ++k) a += d1s[k] * Wf[(long)k * 64 + j];
    out[b * 64 + j] = sigf(a);
  }
}

extern "C" void kernel_launch(void* const* d_in, const int* in_sizes, int n_in,
                              void* d_out, int out_size, void* d_ws, size_t ws_size,
                              hipStream_t stream) {
  const float* x   = (const float*)d_in[0];
  const float* Wi0 = (const float*)d_in[1];
  const float* Wh0 = (const float*)d_in[2];
  const float* b0  = (const float*)d_in[3];
  const float* Wi1 = (const float*)d_in[4];
  const float* Wh1 = (const float*)d_in[5];
  const float* b1  = (const float*)d_in[6];
  const float* Wd0 = (const float*)d_in[7];
  const float* bd0 = (const float*)d_in[8];
  const float* Wd1 = (const float*)d_in[9];
  const float* bd1 = (const float*)d_in[10];
  const float* Wf  = (const float*)d_in[11];
  const float* bf_ = (const float*)d_in[12];
  float* out = (float*)d_out;

  char* ws = (char*)d_ws;
  size_t off = 0;
  auto carve = [&](size_t bytes) {
    void* p = ws + off;
    off += (bytes + 255) & ~(size_t)255;
    return p;
  };
  bf16* WiT0 = (bf16*)carve((size_t)2048 * 256 * 2);
  bf16* WhT0 = (bf16*)carve((size_t)2048 * 512 * 2);
  bf16* WiT1 = (bf16*)carve((size_t)2048 * 512 * 2);
  bf16* WhT1 = (bf16*)carve((size_t)2048 * 512 * 2);
  u64*  h1T  = (u64*)carve((size_t)512 * 64 * 64 * 32);  // 64 MB tagged history
  u64*  h2T  = (u64*)carve((size_t)4 * 64 * 64 * 32);    // 512 KB tagged ring

  // invalidate all tags (tag 0 never matches t+1 >= 1)
  hipMemsetAsync(h1T, 0, (size_t)512 * 64 * 64 * 32, stream);
  hipMemsetAsync(h2T, 0, (size_t)4 * 64 * 64 * 32, stream);

  transpose_k<<<dim3(2048 / 32, 256 / 32), 256, 0, stream>>>(Wi0, WiT0, 256, 2048);
  transpose_k<<<dim3(2048 / 32, 512 / 32), 256, 0, stream>>>(Wh0, WhT0, 512, 2048);
  transpose_k<<<dim3(2048 / 32, 512 / 32), 256, 0, stream>>>(Wi1, WiT1, 512, 2048);
  transpose_k<<<dim3(2048 / 32, 512 / 32), 256, 0, stream>>>(Wh1, WhT1, 512, 2048);

  lstm2_fused_k<<<128, 256, 0, stream>>>(x, WiT0, WhT0, b0, WiT1, WhT1, b1, h1T, h2T);

  head_k<<<64, 256, 0, stream>>>((const u32*)h2T, x, Wd0, bd0, Wd1, bd1, Wf, bf_, out);
}

// Round 7
// 2961.466 us; speedup vs baseline: 1.9234x; 1.6624x over previous
//
#include <hip/hip_runtime.h>
#include <hip/hip_bf16.h>

typedef __hip_bfloat16 bf16;
typedef short bf16x8 __attribute__((ext_vector_type(8)));
typedef float f32x4 __attribute__((ext_vector_type(4)));
typedef unsigned long long u64;
typedef unsigned int u32;

#define MFMA16(A, B, C) __builtin_amdgcn_mfma_f32_16x16x32_bf16(A, B, C, 0, 0, 0)

__device__ __forceinline__ float sigf(float x) { return 1.f / (1.f + __expf(-x)); }
__device__ __forceinline__ float tanh_fast(float x) { return 2.f / (1.f + __expf(-2.f * x)) - 1.f; }

// MALL-direct 16B load (two 8B system-relaxed atomics -> sc0 sc1; bypasses
// L1/L2 so poisoned/stale cached lines can never be observed).
__device__ __forceinline__ bf16x8 ld16(const u64* p) {
  u64 lo = __hip_atomic_load(p, __ATOMIC_RELAXED, __HIP_MEMORY_SCOPE_SYSTEM);
  u64 hi = __hip_atomic_load(p + 1, __ATOMIC_RELAXED, __HIP_MEMORY_SCOPE_SYSTEM);
  union { u64 q[2]; bf16x8 v; } u;
  u.q[0] = lo; u.q[1] = hi;
  return u.v;
}

// ---------------- transpose+cast: WT[n][k] = bf16(W[k][n]) ----------------
__global__ __launch_bounds__(256) void transpose_k(const float* __restrict__ W,
                                                   bf16* __restrict__ WT,
                                                   int K, int N) {
  __shared__ bf16 tile[32][33];
  const int n0 = blockIdx.x * 32, k0 = blockIdx.y * 32;
  const int c = threadIdx.x & 31, r0 = threadIdx.x >> 5;
  for (int i = 0; i < 4; ++i) {
    int r = r0 + 8 * i;
    tile[r][c] = __float2bfloat16(W[(long)(k0 + r) * N + (n0 + c)]);
  }
  __syncthreads();
  for (int i = 0; i < 4; ++i) {
    int r = r0 + 8 * i;
    WT[(long)(n0 + r) * K + (k0 + c)] = tile[c][r];
  }
}

// bulk gather of 16 A-chunks from step matrix mat (u64*, per-t base):
// chunk (slice s=4i+q, row m) = 16B at mat + (s*64 + m)*2
__device__ __forceinline__ void gather16(const u64* __restrict__ mat, int m, int q,
                                         bf16x8* out) {
#pragma unroll
  for (int i = 0; i < 16; ++i) {
    const int s = i * 4 + q;
    out[i] = ld16(mat + ((long)(s << 6) + m) * 2);
  }
}

// ---------------- fused 2-layer persistent LSTM, sentinel dataflow ----------
// 128 WGs x 256 thr. layer = blk>>6, w = blk&63 owns h-cols [8w,8w+8).
// h1D/h2D: [512][64 slices][64 rows][8] bf16 (write-once, full history).
// sent0/sent1: [512][64] u32, zeroed; producer w release-stores sent[t][w]=1
// after its 1KB data slice (release => vmcnt(0) drain: data at MALL first).
// Only wave 0 polls (one 64-lane load covers all 64 producers), then
// __syncthreads releases the WG -> ~64x less poll traffic than r5/r6.
__global__ __launch_bounds__(256, 1) void lstm2_fused_k(
    const float* __restrict__ x,  // [64][512][264] f32
    const bf16* __restrict__ WiT0, const bf16* __restrict__ WhT0,
    const float* __restrict__ bias0,
    const bf16* __restrict__ WiT1, const bf16* __restrict__ WhT1,
    const float* __restrict__ bias1,
    u64* __restrict__ h1D, u64* __restrict__ h2D,
    u32* __restrict__ sent)  // [2][512][64] u32, zeroed
{
  __shared__ short Wis[32 * 520];
  __shared__ short Whs[32 * 520];
  __shared__ float zs[32 * 66];
  __shared__ __align__(16) bf16 hstage[64 * 8];

  const int layer = blockIdx.x >> 6;
  const int w = blockIdx.x & 63;
  const int tid = threadIdx.x;
  const int lane = tid & 63;
  const int wv = tid >> 6;
  const int q = lane >> 4;
  const int r = lane & 15;

  const int K_in = layer ? 512 : 256;
  const bf16* WiT = layer ? WiT1 : WiT0;
  const bf16* WhT = layer ? WhT1 : WhT0;
  const float* bias = layer ? bias1 : bias0;
  u32* s0 = sent;                 // layer-0 sentinels
  u32* s1 = sent + 512 * 64;      // layer-1 sentinels
  u64* hprevD = layer ? h2D : h1D;
  u64* houtD = layer ? h2D : h1D;
  u32* smy = (layer ? s1 : s0);

  // ---- stage weight slices into LDS (reused all 512 steps) ----
  for (int idx = tid; idx < 32 * 64; idx += 256) {
    const int j = idx >> 6, kc = idx & 63;
    const int zc = (j >> 3) * 512 + w * 8 + (j & 7);
    *(bf16x8*)(Whs + j * 520 + kc * 8) = *(const bf16x8*)(WhT + (long)zc * 512 + kc * 8);
  }
  const int csh = layer ? 6 : 5;
  const int cmask = (1 << csh) - 1;
  for (int idx = tid; idx < (32 << csh); idx += 256) {
    const int j = idx >> csh, kc = idx & cmask;
    const int zc = (j >> 3) * 512 + w * 8 + (j & 7);
    *(bf16x8*)(Wis + j * 520 + kc * 8) = *(const bf16x8*)(WiT + (long)zc * K_in + kc * 8);
  }

  const int m = wv * 16 + r;
  const short* wi0p = Wis + r * 520;
  const short* wi1p = Wis + (16 + r) * 520;
  const short* wh0p = Whs + r * 520;
  const short* wh1p = Whs + (16 + r) * 520;

  const int gb = tid & 63;
  const int gc0 = tid >> 6;
  float bias_r[2][4];
  for (int s = 0; s < 2; ++s)
    for (int g = 0; g < 4; ++g)
      bias_r[s][g] = bias[g * 512 + w * 8 + gc0 + 4 * s];
  float creg[2] = {0.f, 0.f};

  __syncthreads();

  for (int t = 0; t < 512; ++t) {
    f32x4 acc0 = {0.f, 0.f, 0.f, 0.f};
    f32x4 acc1 = {0.f, 0.f, 0.f, 0.f};

    if (layer == 0) {
      // x-part first: independent of any producer, overlaps others' step t-1
      bf16x8 ax[8];
      const float* row = x + ((long)m * 512 + t) * 264;
#pragma unroll
      for (int i = 0; i < 8; ++i) {
        const float4 f0 = *(const float4*)(row + i * 32 + q * 8);
        const float4 f1 = *(const float4*)(row + i * 32 + q * 8 + 4);
        union { short s[8]; bf16x8 v8; } o;
        o.s[0] = __builtin_bit_cast(short, __float2bfloat16(f0.x));
        o.s[1] = __builtin_bit_cast(short, __float2bfloat16(f0.y));
        o.s[2] = __builtin_bit_cast(short, __float2bfloat16(f0.z));
        o.s[3] = __builtin_bit_cast(short, __float2bfloat16(f0.w));
        o.s[4] = __builtin_bit_cast(short, __float2bfloat16(f1.x));
        o.s[5] = __builtin_bit_cast(short, __float2bfloat16(f1.y));
        o.s[6] = __builtin_bit_cast(short, __float2bfloat16(f1.z));
        o.s[7] = __builtin_bit_cast(short, __float2bfloat16(f1.w));
        ax[i] = o.v8;
      }
#pragma unroll
      for (int i = 0; i < 8; ++i) {
        const int kk = i * 32;
        acc0 = MFMA16(ax[i], *(const bf16x8*)(wi0p + kk + q * 8), acc0);
        acc1 = MFMA16(ax[i], *(const bf16x8*)(wi1p + kk + q * 8), acc1);
      }
      if (t > 0) {
        if (tid < 64) {  // wave 0 polls all 64 producer sentinels of h1[t-1]
          const u32* sp = s0 + (t - 1) * 64 + tid;
          while (__ballot(__hip_atomic_load(sp, __ATOMIC_RELAXED,
                                            __HIP_MEMORY_SCOPE_SYSTEM) != 0) != ~0ull)
            __builtin_amdgcn_s_sleep(2);
        }
        __syncthreads();
        bf16x8 ah[16];
        gather16(h1D + (long)(t - 1) * 8192, m, q, ah);
#pragma unroll
        for (int i = 0; i < 16; ++i) {
          const int kk = i * 32;
          acc0 = MFMA16(ah[i], *(const bf16x8*)(wh0p + kk + q * 8), acc0);
          acc1 = MFMA16(ah[i], *(const bf16x8*)(wh1p + kk + q * 8), acc1);
        }
      }
    } else {
      // x-part = h1[t]; do it first (layer-0 runs ahead), leave own-layer
      // recurrence (the true critical edge) for last
      if (tid < 64) {
        const u32* sp = s0 + t * 64 + tid;
        while (__ballot(__hip_atomic_load(sp, __ATOMIC_RELAXED,
                                          __HIP_MEMORY_SCOPE_SYSTEM) != 0) != ~0ull)
          __builtin_amdgcn_s_sleep(2);
      }
      __syncthreads();
      bf16x8 ax[16];
      gather16(h1D + (long)t * 8192, m, q, ax);
#pragma unroll
      for (int i = 0; i < 16; ++i) {
        const int kk = i * 32;
        acc0 = MFMA16(ax[i], *(const bf16x8*)(wi0p + kk + q * 8), acc0);
        acc1 = MFMA16(ax[i], *(const bf16x8*)(wi1p + kk + q * 8), acc1);
      }
      if (t > 0) {
        if (tid < 64) {
          const u32* sp = s1 + (t - 1) * 64 + tid;
          while (__ballot(__hip_atomic_load(sp, __ATOMIC_RELAXED,
                                            __HIP_MEMORY_SCOPE_SYSTEM) != 0) != ~0ull)
            __builtin_amdgcn_s_sleep(2);
        }
        __syncthreads();
        bf16x8 ah[16];
        gather16(h2D + (long)(t - 1) * 8192, m, q, ah);
#pragma unroll
        for (int i = 0; i < 16; ++i) {
          const int kk = i * 32;
          acc0 = MFMA16(ah[i], *(const bf16x8*)(wh0p + kk + q * 8), acc0);
          acc1 = MFMA16(ah[i], *(const bf16x8*)(wh1p + kk + q * 8), acc1);
        }
      }
    }

    // D-layout: row(b)=wv*16+q*4+i, col(n)=ntile*16+r  [m89-verified]
    {
      const int brow = wv * 16 + q * 4;
      for (int i = 0; i < 4; ++i) zs[r * 66 + brow + i] = acc0[i];
      for (int i = 0; i < 4; ++i) zs[(16 + r) * 66 + brow + i] = acc1[i];
    }
    __syncthreads();

    for (int s = 0; s < 2; ++s) {
      const int c = gc0 + 4 * s;
      const float zi = zs[(c)*66 + gb] + bias_r[s][0];
      const float zf = zs[(8 + c) * 66 + gb] + bias_r[s][1];
      const float zg = zs[(16 + c) * 66 + gb] + bias_r[s][2];
      const float zo = zs[(24 + c) * 66 + gb] + bias_r[s][3];
      const float cnew = sigf(zf) * creg[s] + sigf(zi) * tanh_fast(zg);
      const float hnew = sigf(zo) * tanh_fast(cnew);
      creg[s] = cnew;
      hstage[gb * 8 + c] = __float2bfloat16(hnew);
    }
    __syncthreads();

    // publish: wave 0 stores the 1KB slice, then lane 0 release-stores the
    // sentinel (release => s_waitcnt vmcnt(0): data at MALL before sentinel)
    if (tid < 64) {
      const u64* src = (const u64*)(hstage + tid * 8);
      u64* dst = houtD + (((long)t * 64 + w) * 64 + tid) * 2;
      __hip_atomic_store(dst, src[0], __ATOMIC_RELAXED, __HIP_MEMORY_SCOPE_SYSTEM);
      __hip_atomic_store(dst + 1, src[1], __ATOMIC_RELAXED, __HIP_MEMORY_SCOPE_SYSTEM);
    }
    if (tid == 0)
      __hip_atomic_store(smy + t * 64 + w, 1u, __ATOMIC_RELEASE, __HIP_MEMORY_SCOPE_AGENT);
  }
}

// ---------------- dense head: concat -> 512 -> 256 -> 64 -> sigmoid ----------
__global__ __launch_bounds__(256) void head_k(
    const u64* __restrict__ h2D,  // [512][64][64][8] bf16; reads t=511
    const float* __restrict__ x,
    const float* __restrict__ Wd0, const float* __restrict__ bd0,
    const float* __restrict__ Wd1, const float* __restrict__ bd1,
    const float* __restrict__ Wf, const float* __restrict__ bfv,
    float* __restrict__ out) {
  const int b = blockIdx.x, tid = threadIdx.x;
  __shared__ float in0[520];
  __shared__ float d0s[512];
  __shared__ float d1s[256];
  if (tid < 64) {
    const int s = tid;
    bf16x8 v = ld16(h2D + (((long)511 * 64 + s) * 64 + b) * 2);
    union { bf16x8 v8; short sh[8]; } u;
    u.v8 = v;
    for (int j = 0; j < 8; ++j)
      in0[s * 8 + j] = __bfloat162float(__builtin_bit_cast(bf16, u.sh[j]));
  }
  if (tid < 8) in0[512 + tid] = x[((long)(b * 512 + 511)) * 264 + 256 + tid];
  __syncthreads();
  for (int j = tid; j < 512; j += 256) {
    float a = bd0[j];
    for (int k = 0; k < 520; ++k) a += in0[k] * Wd0[(long)k * 512 + j];
    d0s[j] = fmaxf(a, 0.f);
  }
  __syncthreads();
  if (tid < 256) {
    const int j = tid;
    float a = bd1[j];
    for (int k = 0; k < 512; ++k) a += d0s[k] * Wd1[(long)k * 256 + j];
    d1s[j] = fmaxf(a, 0.f);
  }
  __syncthreads();
  if (tid < 64) {
    const int j = tid;
    float a = bfv[j];
    for (int k = 0; k < 256; ++k) a += d1s[k] * Wf[(long)k * 64 + j];
    out[b * 64 + j] = sigf(a);
  }
}

extern "C" void kernel_launch(void* const* d_in, const int* in_sizes, int n_in,
                              void* d_out, int out_size, void* d_ws, size_t ws_size,
                              hipStream_t stream) {
  const float* x   = (const float*)d_in[0];
  const float* Wi0 = (const float*)d_in[1];
  const float* Wh0 = (const float*)d_in[2];
  const float* b0  = (const float*)d_in[3];
  const float* Wi1 = (const float*)d_in[4];
  const float* Wh1 = (const float*)d_in[5];
  const float* b1  = (const float*)d_in[6];
  const float* Wd0 = (const float*)d_in[7];
  const float* bd0 = (const float*)d_in[8];
  const float* Wd1 = (const float*)d_in[9];
  const float* bd1 = (const float*)d_in[10];
  const float* Wf  = (const float*)d_in[11];
  const float* bf_ = (const float*)d_in[12];
  float* out = (float*)d_out;

  char* ws = (char*)d_ws;
  size_t off = 0;
  auto carve = [&](size_t bytes) {
    void* p = ws + off;
    off += (bytes + 255) & ~(size_t)255;
    return p;
  };
  u32* sent = (u32*)carve((size_t)2 * 512 * 64 * 4);  // 256 KB sentinels
  const size_t zero_bytes = off;
  bf16* WiT0 = (bf16*)carve((size_t)2048 * 256 * 2);
  bf16* WhT0 = (bf16*)carve((size_t)2048 * 512 * 2);
  bf16* WiT1 = (bf16*)carve((size_t)2048 * 512 * 2);
  bf16* WhT1 = (bf16*)carve((size_t)2048 * 512 * 2);
  u64*  h1D  = (u64*)carve((size_t)512 * 64 * 64 * 16);  // 32 MB bf16 history
  u64*  h2D  = (u64*)carve((size_t)512 * 64 * 64 * 16);  // 32 MB bf16 history

  hipMemsetAsync(sent, 0, zero_bytes, stream);

  transpose_k<<<dim3(2048 / 32, 256 / 32), 256, 0, stream>>>(Wi0, WiT0, 256, 2048);
  transpose_k<<<dim3(2048 / 32, 512 / 32), 256, 0, stream>>>(Wh0, WhT0, 512, 2048);
  transpose_k<<<dim3(2048 / 32, 512 / 32), 256, 0, stream>>>(Wi1, WiT1, 512, 2048);
  transpose_k<<<dim3(2048 / 32, 512 / 32), 256, 0, stream>>>(Wh1, WhT1, 512, 2048);

  lstm2_fused_k<<<128, 256, 0, stream>>>(x, WiT0, WhT0, b0, WiT1, WhT1, b1,
                                         h1D, h2D, sent);

  head_k<<<64, 256, 0, stream>>>(h2D, x, Wd0, bd0, Wd1, bd1, Wf, bf_, out);
}